// Round 10
// baseline (266.068 us; speedup 1.0000x reference)
//
#include <hip/hip_runtime.h>
#include <math.h>

typedef unsigned short u16;
typedef unsigned int   u32;

#define B_   16
#define C_   256
#define HW_  1024
#define N_   16384      // B*H*W rows
#define NE_  8192       // codebook entries
#define K_   256        // feature dim
#define NSPLIT 8
#define CPS  1024       // codes per split
#define NZQ  4194304    // B*C*H*W

typedef _Float16 f16x8 __attribute__((ext_vector_type(8)));
typedef float    f32x16 __attribute__((ext_vector_type(16)));

// output layout: [0, NZQ) = z_q (B,C,H,W); [NZQ] = loss; [NZQ+1, NZQ+1+N_) = indices (as float)

__device__ __forceinline__ u16 f2h(float x) {
    union { _Float16 h; u16 u; } c;
    c.h = (_Float16)x;
    return c.u;
}

// ---------------------------------------------------------------------------
// A: transpose z (B,C,HW) -> z_flat [N_, K_] fp32 + fp16
__global__ void k_transpose_z(const float* __restrict__ z, float* __restrict__ zf,
                              u16* __restrict__ zh) {
    __shared__ float tile[32][33];
    int b   = blockIdx.z;
    int hw0 = blockIdx.x * 32;
    int c0  = blockIdx.y * 32;
    int tx = threadIdx.x;   // 0..31
    int ty = threadIdx.y;   // 0..7
    #pragma unroll
    for (int i = 0; i < 4; ++i) {
        int c = c0 + ty + i * 8;
        tile[ty + i * 8][tx] = z[((size_t)b * C_ + c) * HW_ + hw0 + tx];
    }
    __syncthreads();
    #pragma unroll
    for (int i = 0; i < 4; ++i) {
        int hw = hw0 + ty + i * 8;
        size_t o = ((size_t)b * HW_ + hw) * C_ + c0 + tx;
        float v = tile[tx][ty + i * 8];
        zf[o] = v;
        zh[o] = f2h(v);
    }
}

// ---------------------------------------------------------------------------
// B: codebook GEMM: cb[n][c] = sum_d frozen[n][d] * w[c][d]; fp16 copy;
//    fused c2 (fp32) / c2d (fp64) row-norm accumulation via atomics
//    (c2/c2d zeroed by hipMemsetAsync in the launcher).
__global__ __launch_bounds__(256) void k_codebook_gemm(
        const float* __restrict__ f, const float* __restrict__ w,
        float* __restrict__ cb, u16* __restrict__ cbh,
        float* __restrict__ c2, double* __restrict__ c2d) {
    __shared__ float Fs[16][68];
    __shared__ float Ws[16][68];
    int n0 = blockIdx.x * 64;
    int c0 = blockIdx.y * 64;
    int tid = threadIdx.x;
    int tx = tid & 15, ty = tid >> 4;
    int nl = tid >> 2;            // 0..63
    int kq = (tid & 3) * 4;       // 0,4,8,12
    float acc[4][4] = {};
    for (int kb = 0; kb < K_; kb += 16) {
        float4 fv = *(const float4*)&f[(size_t)(n0 + nl) * K_ + kb + kq];
        float4 wv = *(const float4*)&w[(size_t)(c0 + nl) * K_ + kb + kq];
        __syncthreads();
        Fs[kq + 0][nl] = fv.x; Fs[kq + 1][nl] = fv.y; Fs[kq + 2][nl] = fv.z; Fs[kq + 3][nl] = fv.w;
        Ws[kq + 0][nl] = wv.x; Ws[kq + 1][nl] = wv.y; Ws[kq + 2][nl] = wv.z; Ws[kq + 3][nl] = wv.w;
        __syncthreads();
        #pragma unroll
        for (int k = 0; k < 16; ++k) {
            float4 a = *(float4*)&Fs[k][ty * 4];
            float4 b = *(float4*)&Ws[k][tx * 4];
            float av[4] = {a.x, a.y, a.z, a.w};
            float bv[4] = {b.x, b.y, b.z, b.w};
            #pragma unroll
            for (int i = 0; i < 4; ++i)
                #pragma unroll
                for (int j = 0; j < 4; ++j)
                    acc[i][j] += av[i] * bv[j];
        }
    }
    #pragma unroll
    for (int i = 0; i < 4; ++i) {
        size_t o = (size_t)(n0 + ty * 4 + i) * K_ + c0 + tx * 4;
        *(float4*)&cb[o] = make_float4(acc[i][0], acc[i][1], acc[i][2], acc[i][3]);
        *(ushort4*)&cbh[o] = make_ushort4(f2h(acc[i][0]), f2h(acc[i][1]),
                                          f2h(acc[i][2]), f2h(acc[i][3]));
        double p = (double)acc[i][0] * acc[i][0] + (double)acc[i][1] * acc[i][1]
                 + (double)acc[i][2] * acc[i][2] + (double)acc[i][3] * acc[i][3];
        #pragma unroll
        for (int off = 8; off; off >>= 1) p += __shfl_down(p, off, 16);
        if (tx == 0) {
            atomicAdd(&c2d[n0 + ty * 4 + i], p);
            atomicAdd(&c2[n0 + ty * 4 + i], (float)p);
        }
    }
}

// ---------------------------------------------------------------------------
// C: single-product fp16 MFMA distance scan. score = ||c||^2 - 2 z.c
// B operand (z rows) is wave-private -> lives in REGISTERS (half-K = 32
// VGPR, reloaded per half), A (codes, shared) via LDS. Per ks: 4 A-reads +
// 0 B-reads feed 4 MFMA; staging DMA halves vs r9 (16KB/round).
// TRIPWIRE: WRITE_SIZE balloon = (256,3) cap spilled -> revert to (256,2).
__device__ __forceinline__ void ld_lds16(const void* g, void* l) {
    __builtin_amdgcn_global_load_lds((const __attribute__((address_space(1))) void*)g,
                                     (__attribute__((address_space(3))) void*)l, 16, 0, 0);
}

__global__ __launch_bounds__(256, 3) void k_scan_mfma(
        const u16* __restrict__ zh, const u16* __restrict__ cbh,
        const float* __restrict__ c2, int* __restrict__ t2i) {
    __shared__ __align__(16) u16 sA[8192];   // 128 codes x 64 k, xor-swizzled 16B units
    __shared__ float c2s[128];

    int r0    = blockIdx.x * 128;
    int split = blockIdx.y;
    int tid  = threadIdx.x;
    int wave = tid >> 6, lane = tid & 63;
    int l31 = lane & 31, q = lane >> 5;
    const u16* zrow = zh + (size_t)(r0 + wave * 32 + l31) * K_;

    // running top-2 per lane (z-row = r0 + wave*32 + l31; q-halves merged at end)
    float rs1 = 1e30f, rs2 = 1e30f;
    int   ri1 = 0,     ri2 = 0;

    for (int ct = 0; ct < CPS / 128; ++ct) {
        int code0 = split * CPS + ct * 128;
        f32x16 acc[4];
        #pragma unroll
        for (int i = 0; i < 4; ++i) acc[i] = (f32x16){};
        for (int s = 0; s < 2; ++s) {           // K halves
            // B fragments for this half: chunk (8*(2s+kbi2) + 2ks + q) of 8 f16
            f16x8 bregs[2][4];
            #pragma unroll
            for (int kbi2 = 0; kbi2 < 2; ++kbi2)
                #pragma unroll
                for (int ks = 0; ks < 4; ++ks)
                    bregs[kbi2][ks] =
                        *(const f16x8*)(zrow + (size_t)(8 * (2 * s + kbi2) + 2 * ks + q) * 8);
            #pragma unroll
            for (int kbi2 = 0; kbi2 < 2; ++kbi2) {
                int kb = s * 128 + kbi2 * 64;
                const u16* Ab = cbh + (size_t)code0 * K_ + kb;
                __syncthreads();
                #pragma unroll
                for (int it = 0; it < 4; ++it) {
                    int S = (it * 4 + wave) * 64 + lane;
                    int row = S >> 3, u = S & 7;
                    int k8 = (u ^ (row & 7)) * 8;
                    ld_lds16(Ab + (size_t)row * K_ + k8, &sA[(u32)(it * 4 + wave) * 512]);
                }
                if (s == 0 && kbi2 == 0 && tid < 128) c2s[tid] = c2[code0 + tid];
                __syncthreads();
                #pragma unroll
                for (int ks = 0; ks < 4; ++ks) {
                    f16x8 af[4];
                    #pragma unroll
                    for (int i = 0; i < 4; ++i) {
                        int rowa = i * 32 + l31;
                        u32 ao = (u32)(rowa * 8 + ((ks * 2 + q) ^ (rowa & 7))) * 8;
                        af[i] = *(const f16x8*)&sA[ao];
                    }
                    #pragma unroll
                    for (int i = 0; i < 4; ++i)
                        acc[i] = __builtin_amdgcn_mfma_f32_32x32x16_f16(
                                     af[i], bregs[kbi2][ks], acc[i], 0, 0, 0);
                }
            }
        }
        // epilogue: scores for this 128-code tile, insert into running top-2
        #pragma unroll
        for (int i = 0; i < 4; ++i) {
            float c2r[16];
            #pragma unroll
            for (int h = 0; h < 4; ++h) {
                float4 v = *(float4*)&c2s[i * 32 + 4 * q + 8 * h];
                c2r[h * 4 + 0] = v.x; c2r[h * 4 + 1] = v.y;
                c2r[h * 4 + 2] = v.z; c2r[h * 4 + 3] = v.w;
            }
            int ibase = code0 + i * 32 + 4 * q;
            const f32x16& a = acc[i];
            #pragma unroll
            for (int r = 0; r < 16; ++r) {
                float s = c2r[r] - 2.0f * a[r];
                int idx = ibase + (r & 3) + 8 * (r >> 2);
                if (s < rs1)      { rs2 = rs1; ri2 = ri1; rs1 = s; ri1 = idx; }
                else if (s < rs2) { rs2 = s; ri2 = idx; }
            }
        }
    }
    // merge q-halves (lanes l <-> l^32)
    {
        float os1 = __shfl_xor(rs1, 32, 64);
        int   oi1 = __shfl_xor(ri1, 32, 64);
        float os2 = __shfl_xor(rs2, 32, 64);
        int   oi2 = __shfl_xor(ri2, 32, 64);
        if (os1 < rs1)      { rs2 = rs1; ri2 = ri1; rs1 = os1; ri1 = oi1; }
        else if (os1 < rs2) { rs2 = os1; ri2 = oi1; }
        if (os2 < rs1)      { rs2 = rs1; ri2 = ri1; rs1 = os2; ri1 = oi2; }
        else if (os2 < rs2) { rs2 = os2; ri2 = oi2; }
    }
    if (q == 0) {
        int n = r0 + wave * 32 + l31;
        size_t o = ((size_t)split * N_ + n) * 2;
        t2i[o] = ri1; t2i[o + 1] = ri2;
    }
}

// ---------------------------------------------------------------------------
// D: fp64 rescore of ALL 16 candidates/row; 8 rows/block, 2 rows/wave with
// z cached in registers; candidate-pair per 32-lane half (coalesced cb
// reads), ordered min with index tie-break. Loss partial atomicAdd'ed
// directly into out[NZQ] (zeroed by memset in launcher). One barrier.
__global__ __launch_bounds__(256) void k_finalize(
        const float* __restrict__ zf, const float* __restrict__ cb,
        const double* __restrict__ c2d, const int* __restrict__ t2i,
        float* __restrict__ out) {
    __shared__ int   bidx[8];
    __shared__ float wsum[4];
    __shared__ float tile[8][260];
    int n0 = blockIdx.x * 8;
    int tid = threadIdx.x;
    int wv = tid >> 6, lane = tid & 63;
    int h = lane >> 5, l5 = lane & 31;

    // cache z rows (2 per wave) in registers
    float4 zr[2][2];
    #pragma unroll
    for (int rr = 0; rr < 2; ++rr)
        #pragma unroll
        for (int jj = 0; jj < 2; ++jj)
            zr[rr][jj] = *(const float4*)&zf[(size_t)(n0 + wv * 2 + rr) * K_ + l5 * 4 + jj * 128];

    double bs[2] = {1e300, 1e300};
    int    bi[2] = {0x7fffffff, 0x7fffffff};
    for (int p = 0; p < 8; ++p) {
        int t = 2 * p + h, sp = t >> 1, wsel = t & 1;
        #pragma unroll
        for (int rr = 0; rr < 2; ++rr) {
            int n = n0 + wv * 2 + rr;
            int ci = t2i[((size_t)sp * N_ + n) * 2 + wsel];
            const float* cp = cb + (size_t)ci * K_;
            float4 cv0 = *(const float4*)&cp[l5 * 4];
            float4 cv1 = *(const float4*)&cp[l5 * 4 + 128];
            double acc = (double)zr[rr][0].x * cv0.x + (double)zr[rr][0].y * cv0.y
                       + (double)zr[rr][0].z * cv0.z + (double)zr[rr][0].w * cv0.w
                       + (double)zr[rr][1].x * cv1.x + (double)zr[rr][1].y * cv1.y
                       + (double)zr[rr][1].z * cv1.z + (double)zr[rr][1].w * cv1.w;
            #pragma unroll
            for (int off = 1; off < 32; off <<= 1) acc += __shfl_xor(acc, off, 32);
            double sc = c2d[ci] - 2.0 * acc;
            double so = __shfl_xor(sc, 32, 64);
            int    io = __shfl_xor(ci, 32, 64);
            double s0 = h ? so : sc;  int i0 = h ? io : ci;   // cand 2p
            double s1 = h ? sc : so;  int i1 = h ? ci : io;   // cand 2p+1
            if (s0 < bs[rr] || (s0 == bs[rr] && i0 < bi[rr])) { bs[rr] = s0; bi[rr] = i0; }
            if (s1 < bs[rr] || (s1 == bs[rr] && i1 < bi[rr])) { bs[rr] = s1; bi[rr] = i1; }
        }
    }
    if (lane == 0) {
        #pragma unroll
        for (int rr = 0; rr < 2; ++rr) {
            bidx[wv * 2 + rr] = bi[rr];
            out[(size_t)NZQ + 1 + n0 + wv * 2 + rr] = (float)bi[rr];   // indices
        }
    }
    __syncthreads();

    // phase 2: gather + squared-error partial + stage for transposed write
    float accl = 0.f;
    #pragma unroll
    for (int l = 0; l < 8; ++l) {
        int bi2 = bidx[l];
        float zq = cb[(size_t)bi2 * K_ + tid];
        float d  = zf[(size_t)(n0 + l) * K_ + tid] - zq;
        accl += d * d;
        tile[l][tid] = zq;
    }
    #pragma unroll
    for (int off = 32; off; off >>= 1) accl += __shfl_down(accl, off, 64);
    if ((tid & 63) == 0) wsum[tid >> 6] = accl;
    __syncthreads();
    if (tid == 0)
        atomicAdd(&out[NZQ], (wsum[0] + wsum[1] + wsum[2] + wsum[3]) * (1.25f / (float)NZQ));
    // transposed write: out[(b*C + c)*HW + hw0 + l]
    int b = n0 >> 10, hw0 = n0 & 1023;
    #pragma unroll
    for (int g = 0; g < 2; ++g) {
        float4 v = make_float4(tile[g * 4 + 0][tid], tile[g * 4 + 1][tid],
                               tile[g * 4 + 2][tid], tile[g * 4 + 3][tid]);
        *(float4*)&out[((size_t)b * C_ + tid) * HW_ + hw0 + g * 4] = v;
    }
}

// ---------------------------------------------------------------------------
extern "C" void kernel_launch(void* const* d_in, const int* in_sizes, int n_in,
                              void* d_out, int out_size, void* d_ws, size_t ws_size,
                              hipStream_t stream) {
    const float* z  = (const float*)d_in[0];
    const float* fc = (const float*)d_in[1];
    const float* wt = (const float*)d_in[2];
    float* out = (float*)d_out;

    float* ws = (float*)d_ws;
    const size_t OFF_ZF   = 0;                                   // N*K f
    const size_t OFF_CB   = OFF_ZF + (size_t)N_ * K_;            // NE*K f
    const size_t OFF_C2   = OFF_CB + (size_t)NE_ * K_;           // NE f
    const size_t OFF_C2D  = OFF_C2 + NE_;                        // NE d (2 f each)
    const size_t OFF_T2I  = OFF_C2D + (size_t)NE_ * 2;           // NSPLIT*N*2 i
    const size_t OFF_ZH   = OFF_T2I + (size_t)NSPLIT * N_ * 2;   // fp16 N*K
    const size_t OFF_CBH  = OFF_ZH + (size_t)N_ * K_ / 2;        // fp16 NE*K

    float*  zf   = ws + OFF_ZF;
    float*  cb   = ws + OFF_CB;
    float*  c2   = ws + OFF_C2;
    double* c2d  = (double*)(ws + OFF_C2D);
    int*    t2i  = (int*)(ws + OFF_T2I);
    u16*    zh   = (u16*)(ws + OFF_ZH);
    u16*    cbh  = (u16*)(ws + OFF_CBH);

    // zero the atomic accumulators: c2 (fp32) + c2d (fp64) contiguous, and out[NZQ] (loss)
    hipMemsetAsync(c2, 0, (size_t)NE_ * 4 + (size_t)NE_ * 8, stream);
    hipMemsetAsync((char*)d_out + (size_t)NZQ * 4, 0, 4, stream);

    k_transpose_z<<<dim3(HW_ / 32, C_ / 32, B_), dim3(32, 8), 0, stream>>>(z, zf, zh);
    k_codebook_gemm<<<dim3(NE_ / 64, K_ / 64), 256, 0, stream>>>(fc, wt, cb, cbh, c2, c2d);
    k_scan_mfma<<<dim3(N_ / 128, NSPLIT), 256, 0, stream>>>(zh, cbh, c2, t2i);
    k_finalize<<<N_ / 8, 256, 0, stream>>>(zf, cb, c2d, t2i, out);
}